// Round 1
// baseline (1653.190 us; speedup 1.0000x reference)
//
#include <hip/hip_runtime.h>
#include <hip/hip_bf16.h>

#define BM 128
#define BN 128
#define BK 64
#define LDA 72   // padded bf16 stride: 144B rows -> 16B-aligned b128 reads, 2-way bank alias only
#define LDB 72

typedef __attribute__((ext_vector_type(8))) short short8;
typedef __attribute__((ext_vector_type(4))) short short4v;
typedef __attribute__((ext_vector_type(4))) float float4v;

__device__ __forceinline__ short f2bf(float f) {
  union { float f; unsigned u; } v; v.f = f;
  unsigned r = v.u + 0x7fffu + ((v.u >> 16) & 1u);  // RNE
  return (short)(r >> 16);
}

__global__ __launch_bounds__(256, 2)
void woq_silu_mul_kernel(const float* __restrict__ inp,     // [M,K]
                         const int*   __restrict__ qw,      // [K,N/8]
                         const float* __restrict__ scales,  // [K/G,N]
                         const int*   __restrict__ qzeros,  // [K/G,N/8]
                         const float* __restrict__ bias,    // [N]
                         const float* __restrict__ mulp,    // [M,N]
                         float*       __restrict__ out,     // [M,N]
                         int M, int N, int K, int G)
{
  __shared__ short As[BM * LDA];   // [m][k], bf16 bits
  __shared__ short Bs[BN * LDB];   // [n][k], bf16 bits (dequantized)

  const int tid  = threadIdx.x;
  const int lane = tid & 63;
  const int wave = tid >> 6;
  const int wr = (wave >> 1) * 64;   // wave row offset in tile
  const int wc = (wave & 1) * 64;    // wave col offset in tile

  const int m0 = blockIdx.y * BM;
  const int n0 = blockIdx.x * BN;
  const int N8 = N >> 3;

  float4v acc[4][4];
  #pragma unroll
  for (int i = 0; i < 4; ++i)
    #pragma unroll
    for (int j = 0; j < 4; ++j)
      acc[i][j] = (float4v){0.f, 0.f, 0.f, 0.f};

  // B-staging mapping: thread owns one n8 column (8 n values) and 4 consecutive k rows
  const int n8l  = tid >> 4;   // 0..15
  const int kb   = tid & 15;   // 0..15
  const int kloc = kb * 4;     // 0..60

  // MFMA fragment coords
  const int fm = lane & 15;
  const int fk = (lane >> 4) * 8;

  for (int k0 = 0; k0 < K; k0 += BK) {
    // ---- stage A: 128x64 fp32 -> bf16 LDS ----
    #pragma unroll
    for (int i = 0; i < 8; ++i) {
      int f   = tid + i * 256;      // flat float4 index, consecutive lanes coalesced
      int row = f >> 4;             // 0..127
      int col = (f & 15) * 4;       // 0..60
      float4v a4 = *(const float4v*)(inp + (size_t)(m0 + row) * K + k0 + col);
      short4v h;
      h[0] = f2bf(a4[0]); h[1] = f2bf(a4[1]); h[2] = f2bf(a4[2]); h[3] = f2bf(a4[3]);
      *(short4v*)(&As[row * LDA + col]) = h;
    }

    // ---- stage B: dequant int4 -> bf16 LDS (layout [n][k]) ----
    {
      const int g   = k0 / G;                    // BK=64 divides G=128 -> single group per tile
      const int n8g = (n0 >> 3) + n8l;
      const int zw  = qzeros[(size_t)g * N8 + n8g];
      const float4v s0 = *(const float4v*)(scales + (size_t)g * N + n0 + n8l * 8);
      const float4v s1 = *(const float4v*)(scales + (size_t)g * N + n0 + n8l * 8 + 4);
      float sc[8] = {s0[0], s0[1], s0[2], s0[3], s1[0], s1[1], s1[2], s1[3]};
      int w[4];
      #pragma unroll
      for (int kk = 0; kk < 4; ++kk)
        w[kk] = qw[(size_t)(k0 + kloc + kk) * N8 + n8g];
      #pragma unroll
      for (int j = 0; j < 8; ++j) {
        const float zj = (float)((zw >> (4 * j)) & 0xF);
        const float sj = sc[j];
        short4v h;
        #pragma unroll
        for (int kk = 0; kk < 4; ++kk) {
          int q = (w[kk] >> (4 * j)) & 0xF;
          h[kk] = f2bf(((float)q - zj) * sj);
        }
        *(short4v*)(&Bs[(n8l * 8 + j) * LDB + kloc]) = h;
      }
    }
    __syncthreads();

    // ---- MFMA inner loop ----
    #pragma unroll
    for (int ks = 0; ks < BK; ks += 32) {
      short8 a[4], b[4];
      #pragma unroll
      for (int mt = 0; mt < 4; ++mt)
        a[mt] = *(const short8*)(&As[(wr + mt * 16 + fm) * LDA + ks + fk]);
      #pragma unroll
      for (int nt = 0; nt < 4; ++nt)
        b[nt] = *(const short8*)(&Bs[(wc + nt * 16 + fm) * LDB + ks + fk]);
      #pragma unroll
      for (int mt = 0; mt < 4; ++mt)
        #pragma unroll
        for (int nt = 0; nt < 4; ++nt)
          acc[mt][nt] = __builtin_amdgcn_mfma_f32_16x16x32_bf16(a[mt], b[nt], acc[mt][nt], 0, 0, 0);
    }
    __syncthreads();
  }

  // ---- epilogue: bias + silu + mul, fp32 store ----
  const int cn = lane & 15;
  const int cr = (lane >> 4) * 4;
  #pragma unroll
  for (int mt = 0; mt < 4; ++mt) {
    #pragma unroll
    for (int nt = 0; nt < 4; ++nt) {
      const int n  = n0 + wc + nt * 16 + cn;
      const float bn = bias[n];
      #pragma unroll
      for (int i = 0; i < 4; ++i) {
        const int m = m0 + wr + mt * 16 + cr + i;
        float x = acc[mt][nt][i] + bn;
        float s = x / (1.0f + __expf(-x));
        out[(size_t)m * N + n] = s * mulp[(size_t)m * N + n];
      }
    }
  }
}

extern "C" void kernel_launch(void* const* d_in, const int* in_sizes, int n_in,
                              void* d_out, int out_size, void* d_ws, size_t ws_size,
                              hipStream_t stream) {
  const float* inp    = (const float*)d_in[0];
  const int*   qw     = (const int*)d_in[1];
  const float* scales = (const float*)d_in[2];
  const int*   qzeros = (const int*)d_in[3];
  const float* bias   = (const float*)d_in[4];
  const float* mulp   = (const float*)d_in[5];
  float*       out    = (float*)d_out;

  const int N = in_sizes[4];                                 // bias is [N]
  const int K = (int)(((long long)in_sizes[1] * 8) / N);     // qweight is [K, N/8]
  const int M = (int)((long long)in_sizes[0] / K);           // inp is [M, K]
  const int G = K / (in_sizes[2] / N);                       // scales is [K/G, N]

  dim3 grid(N / BN, M / BM);
  woq_silu_mul_kernel<<<grid, dim3(256), 0, stream>>>(inp, qw, scales, qzeros,
                                                      bias, mulp, out, M, N, K, G);
}

// Round 2
// 811.839 us; speedup vs baseline: 2.0364x; 2.0364x over previous
//
#include <hip/hip_runtime.h>
#include <hip/hip_bf16.h>

typedef __attribute__((ext_vector_type(8))) short short8;
typedef __attribute__((ext_vector_type(4))) short short4v;
typedef __attribute__((ext_vector_type(4))) float float4v;

__device__ __forceinline__ short f2bf(float f) {
  union { float f; unsigned u; } v; v.f = f;
  unsigned r = v.u + 0x7fffu + ((v.u >> 16) & 1u);  // RNE
  return (short)(r >> 16);
}

typedef const __attribute__((address_space(1))) unsigned int* as1_u32p;
typedef __attribute__((address_space(3))) unsigned int* as3_u32p;

__device__ __forceinline__ void gl_lds16(const void* g, void* l) {
  // async global->LDS, 16B/lane, dest = wave-uniform base + lane*16
  __builtin_amdgcn_global_load_lds((as1_u32p)g, (as3_u32p)l, 16, 0, 0);
}

// ---------------------------------------------------------------------------
// Kernel 1: dequant int4 -> bf16 W^T  [N, K]
// tile: 64 k x 16 n8 (=128 n). Lanes along k -> conflict-free LDS transpose,
// per-lane int4 load consumes a full 64B line of qweight (line-exact fetch).
// ---------------------------------------------------------------------------
__global__ __launch_bounds__(256, 2)
void dequant_kernel(const int* __restrict__ qw,      // [K, N/8]
                    const float* __restrict__ scales,// [K/G, N]
                    const int* __restrict__ qzeros,  // [K/G, N/8]
                    short* __restrict__ Bt,          // [N, K] bf16 out
                    int K, int N, int G)
{
  __shared__ short Ls[128 * 64];   // [n_local][k_local]
  const int N8  = N >> 3;
  const int k0  = blockIdx.x * 64;
  const int n80 = blockIdx.y * 16;
  const int g   = k0 / G;
  const int tid  = threadIdx.x;
  const int lane = tid & 63;
  const int w    = tid >> 6;

  const int4 q4 = *(const int4*)(qw + (size_t)(k0 + lane) * N8 + n80 + w * 4);
  const int4 z4 = *(const int4*)(qzeros + (size_t)g * N8 + n80 + w * 4);
  const int qa[4] = {q4.x, q4.y, q4.z, q4.w};
  const int za[4] = {z4.x, z4.y, z4.z, z4.w};

  #pragma unroll
  for (int it = 0; it < 4; ++it) {
    const int n8l = w * 4 + it;                       // 0..15
    const float4v s0 = *(const float4v*)(scales + (size_t)g * N + (n80 + n8l) * 8);
    const float4v s1 = *(const float4v*)(scales + (size_t)g * N + (n80 + n8l) * 8 + 4);
    const float sc[8] = {s0[0], s0[1], s0[2], s0[3], s1[0], s1[1], s1[2], s1[3]};
    const int wq = qa[it], wz = za[it];
    #pragma unroll
    for (int j = 0; j < 8; ++j) {
      const float z = (float)((wz >> (4 * j)) & 0xF);
      const float q = (float)((wq >> (4 * j)) & 0xF);
      Ls[(n8l * 8 + j) * 64 + lane] = f2bf((q - z) * sc[j]);  // 64 lanes contiguous: no conflict
    }
  }
  __syncthreads();

  #pragma unroll
  for (int it = 0; it < 4; ++it) {
    const int c   = tid + it * 256;       // 0..1023
    const int row = c >> 3;               // 0..127
    const int off = (c & 7) * 8;          // element col
    const short8 v = *(const short8*)(&Ls[row * 64 + off]);
    *(short8*)(Bt + (size_t)(n80 * 8 + row) * K + k0 + off) = v;
  }
}

// ---------------------------------------------------------------------------
// Kernel 2: A fp32 -> bf16 [M, K]
// ---------------------------------------------------------------------------
__global__ __launch_bounds__(256, 4)
void aconv_kernel(const float* __restrict__ in, short* __restrict__ out, long long n)
{
  const long long i = ((long long)blockIdx.x * blockDim.x + threadIdx.x) * 8;
  if (i >= n) return;
  const float4v a = *(const float4v*)(in + i);
  const float4v b = *(const float4v*)(in + i + 4);
  short8 h;
  h[0] = f2bf(a[0]); h[1] = f2bf(a[1]); h[2] = f2bf(a[2]); h[3] = f2bf(a[3]);
  h[4] = f2bf(b[0]); h[5] = f2bf(b[1]); h[6] = f2bf(b[2]); h[7] = f2bf(b[3]);
  *(short8*)(out + i) = h;
}

// ---------------------------------------------------------------------------
// Kernel 3: bf16 GEMM (m97 structure) + bias + silu + mul epilogue
// A [M,K] bf16, Bt [N,K] bf16. 128x128 tile, BK=64, global_load_lds width 16.
// ---------------------------------------------------------------------------
__global__ __launch_bounds__(256, 2)
void gemm_silu_mul_kernel(const short* __restrict__ A,
                          const short* __restrict__ Bt,
                          const float* __restrict__ bias,
                          const float* __restrict__ mulp,
                          float*       __restrict__ out,
                          int M, int N, int K)
{
  __shared__ short As[128 * 64];   // [m][k] unpadded (global_load_lds layout)
  __shared__ short Bs[128 * 64];   // [n][k]

  const int tid  = threadIdx.x;
  const int lane = tid & 63;
  const int wave = tid >> 6;
  const int wr = (wave >> 1) * 64;
  const int wc = (wave & 1) * 64;
  const int m0 = blockIdx.y * 128;
  const int n0 = blockIdx.x * 128;

  float4v acc[4][4];
  #pragma unroll
  for (int i = 0; i < 4; ++i)
    #pragma unroll
    for (int j = 0; j < 4; ++j)
      acc[i][j] = (float4v){0.f, 0.f, 0.f, 0.f};

  const int fm = lane & 15;
  const int fk = (lane >> 4) * 8;
  const int srow = lane >> 3;        // 0..7 within 8-row chunk
  const int scol = (lane & 7) * 8;   // k element offset

  for (int k0 = 0; k0 < K; k0 += 64) {
    #pragma unroll
    for (int c = 0; c < 4; ++c) {
      const int chunk = wave * 4 + c;          // 0..15 -> rows [chunk*8, chunk*8+8)
      const int row   = chunk * 8 + srow;
      gl_lds16(A  + (size_t)(m0 + row) * K + k0 + scol, &As[chunk * 512]);
      gl_lds16(Bt + (size_t)(n0 + row) * K + k0 + scol, &Bs[chunk * 512]);
    }
    __syncthreads();

    #pragma unroll
    for (int ks = 0; ks < 64; ks += 32) {
      short8 a[4], b[4];
      #pragma unroll
      for (int mt = 0; mt < 4; ++mt)
        a[mt] = *(const short8*)(&As[(wr + mt * 16 + fm) * 64 + ks + fk]);
      #pragma unroll
      for (int nt = 0; nt < 4; ++nt)
        b[nt] = *(const short8*)(&Bs[(wc + nt * 16 + fm) * 64 + ks + fk]);
      #pragma unroll
      for (int mt = 0; mt < 4; ++mt)
        #pragma unroll
        for (int nt = 0; nt < 4; ++nt)
          acc[mt][nt] = __builtin_amdgcn_mfma_f32_16x16x32_bf16(a[mt], b[nt], acc[mt][nt], 0, 0, 0);
    }
    __syncthreads();
  }

  const int cn = lane & 15;
  const int cr = (lane >> 4) * 4;
  #pragma unroll
  for (int mt = 0; mt < 4; ++mt) {
    #pragma unroll
    for (int nt = 0; nt < 4; ++nt) {
      const int n  = n0 + wc + nt * 16 + cn;
      const float bn = bias[n];
      #pragma unroll
      for (int i = 0; i < 4; ++i) {
        const int m = m0 + wr + mt * 16 + cr + i;
        float x = acc[mt][nt][i] + bn;
        float s = x / (1.0f + __expf(-x));
        out[(size_t)m * N + n] = s * mulp[(size_t)m * N + n];
      }
    }
  }
}

// ---------------------------------------------------------------------------
// Fallback: round-1 fused kernel (used only if ws_size is too small)
// ---------------------------------------------------------------------------
#define BM 128
#define BN 128
#define BK 64
#define LDA 72
#define LDB 72

__global__ __launch_bounds__(256, 2)
void woq_silu_mul_kernel(const float* __restrict__ inp, const int* __restrict__ qw,
                         const float* __restrict__ scales, const int* __restrict__ qzeros,
                         const float* __restrict__ bias, const float* __restrict__ mulp,
                         float* __restrict__ out, int M, int N, int K, int G)
{
  __shared__ short As[BM * LDA];
  __shared__ short Bs[BN * LDB];
  const int tid  = threadIdx.x;
  const int lane = tid & 63;
  const int wave = tid >> 6;
  const int wr = (wave >> 1) * 64;
  const int wc = (wave & 1) * 64;
  const int m0 = blockIdx.y * BM;
  const int n0 = blockIdx.x * BN;
  const int N8 = N >> 3;
  float4v acc[4][4];
  #pragma unroll
  for (int i = 0; i < 4; ++i)
    #pragma unroll
    for (int j = 0; j < 4; ++j)
      acc[i][j] = (float4v){0.f, 0.f, 0.f, 0.f};
  const int n8l  = tid >> 4;
  const int kloc = (tid & 15) * 4;
  const int fm = lane & 15;
  const int fk = (lane >> 4) * 8;
  for (int k0 = 0; k0 < K; k0 += BK) {
    #pragma unroll
    for (int i = 0; i < 8; ++i) {
      int f = tid + i * 256;
      int row = f >> 4;
      int col = (f & 15) * 4;
      float4v a4 = *(const float4v*)(inp + (size_t)(m0 + row) * K + k0 + col);
      short4v h;
      h[0] = f2bf(a4[0]); h[1] = f2bf(a4[1]); h[2] = f2bf(a4[2]); h[3] = f2bf(a4[3]);
      *(short4v*)(&As[row * LDA + col]) = h;
    }
    {
      const int g = k0 / G;
      const int n8g = (n0 >> 3) + n8l;
      const int zw = qzeros[(size_t)g * N8 + n8g];
      const float4v s0 = *(const float4v*)(scales + (size_t)g * N + n0 + n8l * 8);
      const float4v s1 = *(const float4v*)(scales + (size_t)g * N + n0 + n8l * 8 + 4);
      float sc[8] = {s0[0], s0[1], s0[2], s0[3], s1[0], s1[1], s1[2], s1[3]};
      int w[4];
      #pragma unroll
      for (int kk = 0; kk < 4; ++kk)
        w[kk] = qw[(size_t)(k0 + kloc + kk) * N8 + n8g];
      #pragma unroll
      for (int j = 0; j < 8; ++j) {
        const float zj = (float)((w[0], (zw >> (4 * j)) & 0xF));
        const float sj = sc[j];
        short4v h;
        #pragma unroll
        for (int kk = 0; kk < 4; ++kk) {
          int q = (w[kk] >> (4 * j)) & 0xF;
          h[kk] = f2bf(((float)q - zj) * sj);
        }
        *(short4v*)(&Bs[(n8l * 8 + j) * LDB + kloc]) = h;
      }
    }
    __syncthreads();
    #pragma unroll
    for (int ks = 0; ks < BK; ks += 32) {
      short8 a[4], b[4];
      #pragma unroll
      for (int mt = 0; mt < 4; ++mt)
        a[mt] = *(const short8*)(&As[(wr + mt * 16 + fm) * LDA + ks + fk]);
      #pragma unroll
      for (int nt = 0; nt < 4; ++nt)
        b[nt] = *(const short8*)(&Bs[(wc + nt * 16 + fm) * LDB + ks + fk]);
      #pragma unroll
      for (int mt = 0; mt < 4; ++mt)
        #pragma unroll
        for (int nt = 0; nt < 4; ++nt)
          acc[mt][nt] = __builtin_amdgcn_mfma_f32_16x16x32_bf16(a[mt], b[nt], acc[mt][nt], 0, 0, 0);
    }
    __syncthreads();
  }
  const int cn = lane & 15;
  const int cr = (lane >> 4) * 4;
  #pragma unroll
  for (int mt = 0; mt < 4; ++mt) {
    #pragma unroll
    for (int nt = 0; nt < 4; ++nt) {
      const int n = n0 + wc + nt * 16 + cn;
      const float bn = bias[n];
      #pragma unroll
      for (int i = 0; i < 4; ++i) {
        const int m = m0 + wr + mt * 16 + cr + i;
        float x = acc[mt][nt][i] + bn;
        float s = x / (1.0f + __expf(-x));
        out[(size_t)m * N + n] = s * mulp[(size_t)m * N + n];
      }
    }
  }
}

extern "C" void kernel_launch(void* const* d_in, const int* in_sizes, int n_in,
                              void* d_out, int out_size, void* d_ws, size_t ws_size,
                              hipStream_t stream) {
  const float* inp    = (const float*)d_in[0];
  const int*   qw     = (const int*)d_in[1];
  const float* scales = (const float*)d_in[2];
  const int*   qzeros = (const int*)d_in[3];
  const float* bias   = (const float*)d_in[4];
  const float* mulp   = (const float*)d_in[5];
  float*       out    = (float*)d_out;

  const int N = in_sizes[4];
  const int K = (int)(((long long)in_sizes[1] * 8) / N);
  const int M = (int)((long long)in_sizes[0] / K);
  const int G = K / (in_sizes[2] / N);

  const size_t btBytes = (size_t)N * K * sizeof(short);
  const size_t aBytes  = (size_t)M * K * sizeof(short);

  if (ws_size >= btBytes + aBytes) {
    short* Bt  = (short*)d_ws;
    short* Abf = (short*)((char*)d_ws + btBytes);

    dim3 dq_grid(K / 64, (N / 8) / 16);
    dequant_kernel<<<dq_grid, dim3(256), 0, stream>>>(qw, scales, qzeros, Bt, K, N, G);

    const long long nA = (long long)M * K;
    aconv_kernel<<<dim3((unsigned)((nA / 8 + 255) / 256)), dim3(256), 0, stream>>>(inp, Abf, nA);

    dim3 grid(N / 128, M / 128);
    gemm_silu_mul_kernel<<<grid, dim3(256), 0, stream>>>(Abf, Bt, bias, mulp, out, M, N, K);
  } else {
    dim3 grid(N / BN, M / BM);
    woq_silu_mul_kernel<<<grid, dim3(256), 0, stream>>>(inp, qw, scales, qzeros,
                                                        bias, mulp, out, M, N, K, G);
  }
}